// Round 4
// baseline (286.808 us; speedup 1.0000x reference)
//
#include <hip/hip_runtime.h>
#include <math.h>

// ---------------------------------------------------------------------------
// PatchEmbedding: gather 9x9x3 patches from frames, x@W1+b1 -> GELU -> @W2+b2
// B=4, T=16, C=3, H=W=256, N=8192, patch_dim=243, EMBED=768
//
// R3 post-mortem: 228.7us (-14.8). 8-wave/XCD-swizzle worked; gemm2 now
// LDS-READ-PIPE bound: 64x32 per-wave tile = 0.75 ds_read_b128 per MFMA ->
// ~42us of LDS pipe vs 18.6us MFMA, 28us HBM.
//
// R4: 128^2 tile, 4 waves (64x64 per wave = 0.5 reads/MFMA), BK=32 ->
// LDS 32KB/block -> 4 blocks/CU (16 waves/CU kept, VGPR~100 <= 128).
// New conflict-free LDS layout for 64B rows: two tile-rows per 128B phys row,
// slot XOR (row>>1)&3; verified store/read round-trip = identity and b128
// bank demand = structural minimum (8/bank). NT stores for C (USE_NT) so the
// 100MB fp32 write stream doesn't thrash the L2 serving A-panel re-reads.
// K-order trick unchanged: X and W1T use permuted k' = c*81 + i*9 + j.
// r4 lesson (prev session): no bucket-sorting the gather.
// ---------------------------------------------------------------------------

#define USE_NT 1

typedef __attribute__((ext_vector_type(8))) short short8;
typedef __attribute__((ext_vector_type(4))) float floatx4;

#define M_ROWS 32768      // B*N = 4*8192
#define KPAD   256        // patch_dim 243 padded to 256
#define EMB    768

typedef __attribute__((address_space(1))) const void g_void;
typedef __attribute__((address_space(3))) void l_void;

__device__ __forceinline__ unsigned short f2bf(float f) {
    union { float f; unsigned int i; } w;
    w.f = f;
    unsigned int x = w.i;
    x += 0x7fffu + ((x >> 16) & 1u);   // round-to-nearest-even
    return (unsigned short)(x >> 16);
}

// tanh-form GELU: max abs deviation from exact erf-GELU < 1e-3.
__device__ __forceinline__ float gelu_f(float x) {
    float x3 = x * x * x;
    float y  = 1.5957691216f * (x + 0.044715f * x3);   // 2*sqrt(2/pi)*(...)
    float e  = __expf(y);                               // e^{2z}
    float th = 1.0f - 2.0f / (e + 1.0f);                // tanh(z)
    return 0.5f * x * (1.0f + th);
}

// ---- prep: W1 (243x768 f32) -> W1T (768x256 bf16, zero-pad, permuted k') ----
__global__ void k_transpose_w1(const float* __restrict__ W1,
                               unsigned short* __restrict__ W1T) {
    int idx = blockIdx.x * 256 + threadIdx.x;   // 768*256 total
    int n  = idx >> 8;        // 0..767
    int kp = idx & 255;       // permuted k': c*81 + i*9 + j
    unsigned short v = 0;
    if (kp < 243) {
        int c = kp / 81;
        int r = kp - c * 81;
        int i = r / 9;
        int j = r - i * 9;
        int e = i * 27 + j * 3 + c;   // reference order
        v = f2bf(W1[e * EMB + n]);
    }
    W1T[idx] = v;
}

// ---- prep: W2 (768x768 f32) -> W2T (768x768 bf16), LDS-tiled transpose ----
__global__ void k_transpose_w2(const float* __restrict__ W2,
                               unsigned short* __restrict__ W2T) {
    __shared__ float tile[32][33];
    int tx = threadIdx.x & 31, ty = threadIdx.x >> 5;   // 32 x 8
    int k0 = blockIdx.x * 32, n0 = blockIdx.y * 32;
#pragma unroll
    for (int i = 0; i < 4; ++i)
        tile[ty + i * 8][tx] = W2[(size_t)(k0 + ty + i * 8) * EMB + n0 + tx];
    __syncthreads();
#pragma unroll
    for (int i = 0; i < 4; ++i)
        W2T[(size_t)(n0 + ty + i * 8) * EMB + k0 + tx] = f2bf(tile[tx][ty + i * 8]);
}

// ---- gather patches -> X (32768 x 256 bf16), channel-major order k' --------
__global__ void k_gather(const float* __restrict__ frames,
                         const float* __restrict__ coords,
                         const int* __restrict__ t_src,
                         unsigned short* __restrict__ X) {
    int row  = blockIdx.x * 4 + (threadIdx.x >> 6);   // 0..32767
    int lane = threadIdx.x & 63;
    int b = row >> 13;

    float cu = coords[row * 2 + 0];
    float cv = coords[row * 2 + 1];
    int u = (int)(cu * 255.0f);   // exact fp32 math, matches reference
    int v = (int)(cv * 255.0f);
    int t = t_src[row];

    const float* fb = frames + (size_t)(b * 16 + t) * (3 * 256 * 256);
    unsigned short* xr = X + (size_t)row * KPAD;

#pragma unroll
    for (int it = 0; it < 4; ++it) {
        int kp = lane + it * 64;            // permuted index c*81 + i*9 + j
        unsigned short val = 0;
        if (kp < 243) {
            int c = kp / 81;
            int r = kp - c * 81;
            int i = r / 9;
            int j = r - i * 9;
            int y = v + i - 4; y = (y < 0) ? 0 : (y > 255 ? 255 : y);
            int x = u + j - 4; x = (x < 0) ? 0 : (x > 255 ? 255 : x);
            val = f2bf(fb[(size_t)c * 65536 + y * 256 + x]);
        }
        xr[kp] = val;
    }
}

// ---- MFMA GEMM body (shared by k_gemm1 / k_gemm2) -------------------------
// 128x128 tile / 4 waves (each 64x64 via 4x4 16x16x32). BK=32, double-buffered
// LDS (2 x 8KB per operand = 32KB total), global_load_lds width=16 issued
// right after the single per-iteration barrier.
// LDS layout (per 128x32 tile): two tile-rows per 128B physical row; logical
// 16B slot s (s=0..3, k-chunk) of tile-row r lives at byte
//   (r>>1)*128 + (r&1)*64 + (s ^ ((r>>1)&3))*16
// Staged linearly by gll (dest = chunk*1KB + lane*16B); source address is
// pre-swizzled so the round-trip is identity (verified algebraically).
// Grid is FLAT 1536 = 256 M-tiles x 6 N-tiles, XCD-chunk swizzled, y-fastest.
template <int K, bool GELU_, bool OUT_F32>
static __device__ __forceinline__
void gemm_body(const unsigned short* __restrict__ A,
               const unsigned short* __restrict__ BT,
               const float* __restrict__ bias,
               void* __restrict__ Cv) {
    __shared__ unsigned short As[2][128 * 32];   // 8 KB each
    __shared__ unsigned short Bs[2][128 * 32];   // total LDS = 32 KB

    const int tid  = threadIdx.x;
    const int wave = tid >> 6;      // 0..3
    const int lane = tid & 63;
    const int wm = (wave >> 1) * 64;   // wave row offset
    const int wn = (wave & 1) * 64;    // wave col offset
    const int lm = lane & 15;
    const int lq = lane >> 4;          // k-chunk 0..3 (8 elems each)

    // XCD-chunked bijective swizzle (nwg=1536, 192/XCD), y-fastest so the 6
    // blocks sharing one A-panel are consecutive logical tiles -> same XCD L2.
    const int bid = blockIdx.x;
    const int swz = (bid & 7) * 192 + (bid >> 3);
    const int by  = swz % 6;
    const int bx  = swz / 6;
    const int m0 = bx * 128;
    const int n0 = by * 128;

    floatx4 acc[4][4];
#pragma unroll
    for (int i = 0; i < 4; ++i)
#pragma unroll
        for (int j = 0; j < 4; ++j)
            acc[i][j] = (floatx4){0.f, 0.f, 0.f, 0.f};

    const unsigned short* Ag = A  + (size_t)m0 * K;
    const unsigned short* Bg = BT + (size_t)n0 * K;

    // staging: chunk c (0..7) = 1KB of LDS = tile rows 16c..16c+15.
    // lane l -> tile-row_local 2*(l>>3) + ((l>>2)&1), phys slot l&3,
    // logical k-chunk (l&3) ^ ((l>>3)&3)  (since (row>>1)&3 == (l>>3)&3).
    const int rloc   = 2 * (lane >> 3) + ((lane >> 2) & 1);
    const int kchunk = (lane & 3) ^ ((lane >> 3) & 3);
    const int c0 = 2 * wave, c1 = 2 * wave + 1;
    const size_t o0 = (size_t)(c0 * 16 + rloc) * K + (kchunk << 3);
    const size_t o1 = (size_t)(c1 * 16 + rloc) * K + (kchunk << 3);

    // frag read offsets (in shorts): row r, k-chunk lq ->
    //   (r>>1)*64 + (r&1)*32 + ((lq ^ ((r>>1)&3)) << 3)
    int aoff[4], boff[4];
#pragma unroll
    for (int mi = 0; mi < 4; ++mi) {
        int r = wm + mi * 16 + lm;
        aoff[mi] = (r >> 1) * 64 + (r & 1) * 32 + ((lq ^ ((r >> 1) & 3)) << 3);
        int rb = wn + mi * 16 + lm;
        boff[mi] = (rb >> 1) * 64 + (rb & 1) * 32 + ((lq ^ ((rb >> 1) & 3)) << 3);
    }

    // prologue: issue tile 0 into buffer 0
    __builtin_amdgcn_global_load_lds((g_void*)(Ag + o0), (l_void*)(&As[0][c0 * 512]), 16, 0, 0);
    __builtin_amdgcn_global_load_lds((g_void*)(Ag + o1), (l_void*)(&As[0][c1 * 512]), 16, 0, 0);
    __builtin_amdgcn_global_load_lds((g_void*)(Bg + o0), (l_void*)(&Bs[0][c0 * 512]), 16, 0, 0);
    __builtin_amdgcn_global_load_lds((g_void*)(Bg + o1), (l_void*)(&Bs[0][c1 * 512]), 16, 0, 0);

    int buf = 0;
#pragma unroll 2
    for (int k0 = 0; k0 < K; k0 += 32) {
        __syncthreads();   // drains gll for tile(k0), closes reads of buf^1

        if (k0 + 32 < K) {
            __builtin_amdgcn_global_load_lds((g_void*)(Ag + o0 + k0 + 32),
                                             (l_void*)(&As[buf ^ 1][c0 * 512]), 16, 0, 0);
            __builtin_amdgcn_global_load_lds((g_void*)(Ag + o1 + k0 + 32),
                                             (l_void*)(&As[buf ^ 1][c1 * 512]), 16, 0, 0);
            __builtin_amdgcn_global_load_lds((g_void*)(Bg + o0 + k0 + 32),
                                             (l_void*)(&Bs[buf ^ 1][c0 * 512]), 16, 0, 0);
            __builtin_amdgcn_global_load_lds((g_void*)(Bg + o1 + k0 + 32),
                                             (l_void*)(&Bs[buf ^ 1][c1 * 512]), 16, 0, 0);
        }

        short8 af[4], bfr[4];
#pragma unroll
        for (int mi = 0; mi < 4; ++mi)
            af[mi] = *(const short8*)(&As[buf][aoff[mi]]);
#pragma unroll
        for (int ni = 0; ni < 4; ++ni)
            bfr[ni] = *(const short8*)(&Bs[buf][boff[ni]]);

#pragma unroll
        for (int mi = 0; mi < 4; ++mi)
#pragma unroll
            for (int ni = 0; ni < 4; ++ni)
                acc[mi][ni] = __builtin_amdgcn_mfma_f32_16x16x32_bf16(
                    af[mi], bfr[ni], acc[mi][ni], 0, 0, 0);
        buf ^= 1;
    }

    // epilogue: D[row][col], row = lq*4 + r, col = lm within each 16x16 tile
#pragma unroll
    for (int ni = 0; ni < 4; ++ni) {
        int col = n0 + wn + ni * 16 + lm;
        float bs = bias[col];
#pragma unroll
        for (int mi = 0; mi < 4; ++mi) {
            int rowb = m0 + wm + mi * 16 + lq * 4;
#pragma unroll
            for (int r = 0; r < 4; ++r) {
                float x = acc[mi][ni][r] + bs;
                if (GELU_)
                    x = gelu_f(x);
                size_t idx = (size_t)(rowb + r) * EMB + col;
                if (OUT_F32) {
#if USE_NT
                    __builtin_nontemporal_store(x, &((float*)Cv)[idx]);
#else
                    ((float*)Cv)[idx] = x;
#endif
                } else {
#if USE_NT
                    __builtin_nontemporal_store(f2bf(x), &((unsigned short*)Cv)[idx]);
#else
                    ((unsigned short*)Cv)[idx] = f2bf(x);
#endif
                }
            }
        }
    }
}

// distinct names so rocprof shows each GEMM separately
__global__ __launch_bounds__(256, 4)
void k_gemm1(const unsigned short* __restrict__ A, const unsigned short* __restrict__ BT,
             const float* __restrict__ bias, unsigned short* __restrict__ C) {
    gemm_body<KPAD, true, false>(A, BT, bias, (void*)C);
}

__global__ __launch_bounds__(256, 4)
void k_gemm2(const unsigned short* __restrict__ A, const unsigned short* __restrict__ BT,
             const float* __restrict__ bias, float* __restrict__ C) {
    gemm_body<EMB, false, true>(A, BT, bias, (void*)C);
}

// ---------------------------------------------------------------------------
extern "C" void kernel_launch(void* const* d_in, const int* in_sizes, int n_in,
                              void* d_out, int out_size, void* d_ws, size_t ws_size,
                              hipStream_t stream) {
    const float* frames = (const float*)d_in[0];
    const float* coords = (const float*)d_in[1];
    const int*   t_src  = (const int*)d_in[2];
    const float* W1     = (const float*)d_in[3];
    const float* b1     = (const float*)d_in[4];
    const float* W2     = (const float*)d_in[5];
    const float* b2     = (const float*)d_in[6];
    float* out = (float*)d_out;

    char* ws = (char*)d_ws;
    // workspace layout:
    //   X    : 32768*256*2 = 16,777,216 B  (bf16, permuted k')
    //   Hbuf : 32768*768*2 = 50,331,648 B  (bf16)
    //   W1T  : 768*256*2   =    393,216 B  (bf16, permuted k')
    //   W2T  : 768*768*2   =  1,179,648 B  (bf16)
    unsigned short* X    = (unsigned short*)(ws);
    unsigned short* Hbuf = (unsigned short*)(ws + 16777216);
    unsigned short* W1T  = (unsigned short*)(ws + 16777216 + 50331648);
    unsigned short* W2T  = (unsigned short*)(ws + 16777216 + 50331648 + 393216);

    // prep transposes (tiny)
    k_transpose_w1<<<768, 256, 0, stream>>>(W1, W1T);
    k_transpose_w2<<<dim3(24, 24), 256, 0, stream>>>(W2, W2T);

    // gather patches (one wave per row, channel-major element order)
    k_gather<<<M_ROWS / 4, 256, 0, stream>>>(frames, coords, t_src, X);

    // GEMM1: H = gelu(X @ W1 + b1)   (K = 256 padded), bf16 out
    k_gemm1<<<1536, 256, 0, stream>>>(X, W1T, b1, Hbuf);

    // GEMM2: out = H @ W2 + b2       (K = 768), fp32 out
    k_gemm2<<<1536, 256, 0, stream>>>(Hbuf, W2T, b2, out);
}

// Round 5
// 230.505 us; speedup vs baseline: 1.2443x; 1.2443x over previous
//
#include <hip/hip_runtime.h>
#include <math.h>

// ---------------------------------------------------------------------------
// PatchEmbedding: gather 9x9x3 patches from frames, x@W1+b1 -> GELU -> @W2+b2
// B=4, T=16, C=3, H=W=256, N=8192, patch_dim=243, EMBED=768
//
// R4 post-mortem: BK=32 regressed (gemm2 84us) — barrier window 320cy < gll
// flight; occupancy rose to 31% but perf fell => window-bound, not occupancy.
// NT stores unvalidated, dropped.
//
// R5: 128x256 block tile, 8 waves each owning 64x64 (A shared x4, B x2):
//   reads/MFMA 0.75 -> 0.25 (LDS-read pipe ~35 -> ~12us), window 1280cy/SIMD.
//   SINGLE-buffered 48KB LDS -> 2 blocks/CU, 16 waves/CU. Split-ks liveness
//   keeps VGPR ~120: read ks0 / MFMA ks0 / read ks1 / BARRIER(frees LDS) /
//   stage next (6 gll) / MFMA ks1 / BARRIER(drains vmcnt -> tile landed).
//   All barriers are __syncthreads (full drain) — conservative, race-free.
// Grid 768 = 256 Mx3 N tiles, XCD-chunked y-fastest (A-panel L2 locality).
// K-order trick unchanged: X and W1T use permuted k' = c*81 + i*9 + j.
// r4 lesson (prev session): no bucket-sorting the gather.
// ---------------------------------------------------------------------------

typedef __attribute__((ext_vector_type(8))) short short8;
typedef __attribute__((ext_vector_type(4))) float floatx4;

#define M_ROWS 32768      // B*N = 4*8192
#define KPAD   256        // patch_dim 243 padded to 256
#define EMB    768

typedef __attribute__((address_space(1))) const void g_void;
typedef __attribute__((address_space(3))) void l_void;

__device__ __forceinline__ unsigned short f2bf(float f) {
    union { float f; unsigned int i; } w;
    w.f = f;
    unsigned int x = w.i;
    x += 0x7fffu + ((x >> 16) & 1u);   // round-to-nearest-even
    return (unsigned short)(x >> 16);
}

// tanh-form GELU: max abs deviation from exact erf-GELU < 1e-3.
__device__ __forceinline__ float gelu_f(float x) {
    float x3 = x * x * x;
    float y  = 1.5957691216f * (x + 0.044715f * x3);   // 2*sqrt(2/pi)*(...)
    float e  = __expf(y);                               // e^{2z}
    float th = 1.0f - 2.0f / (e + 1.0f);                // tanh(z)
    return 0.5f * x * (1.0f + th);
}

// ---- prep: W1 (243x768 f32) -> W1T (768x256 bf16, zero-pad, permuted k') ----
__global__ void k_transpose_w1(const float* __restrict__ W1,
                               unsigned short* __restrict__ W1T) {
    int idx = blockIdx.x * 256 + threadIdx.x;   // 768*256 total
    int n  = idx >> 8;        // 0..767
    int kp = idx & 255;       // permuted k': c*81 + i*9 + j
    unsigned short v = 0;
    if (kp < 243) {
        int c = kp / 81;
        int r = kp - c * 81;
        int i = r / 9;
        int j = r - i * 9;
        int e = i * 27 + j * 3 + c;   // reference order
        v = f2bf(W1[e * EMB + n]);
    }
    W1T[idx] = v;
}

// ---- prep: W2 (768x768 f32) -> W2T (768x768 bf16), LDS-tiled transpose ----
__global__ void k_transpose_w2(const float* __restrict__ W2,
                               unsigned short* __restrict__ W2T) {
    __shared__ float tile[32][33];
    int tx = threadIdx.x & 31, ty = threadIdx.x >> 5;   // 32 x 8
    int k0 = blockIdx.x * 32, n0 = blockIdx.y * 32;
#pragma unroll
    for (int i = 0; i < 4; ++i)
        tile[ty + i * 8][tx] = W2[(size_t)(k0 + ty + i * 8) * EMB + n0 + tx];
    __syncthreads();
#pragma unroll
    for (int i = 0; i < 4; ++i)
        W2T[(size_t)(n0 + ty + i * 8) * EMB + k0 + tx] = f2bf(tile[tx][ty + i * 8]);
}

// ---- gather patches -> X (32768 x 256 bf16), channel-major order k' --------
__global__ void k_gather(const float* __restrict__ frames,
                         const float* __restrict__ coords,
                         const int* __restrict__ t_src,
                         unsigned short* __restrict__ X) {
    int row  = blockIdx.x * 4 + (threadIdx.x >> 6);   // 0..32767
    int lane = threadIdx.x & 63;
    int b = row >> 13;

    float cu = coords[row * 2 + 0];
    float cv = coords[row * 2 + 1];
    int u = (int)(cu * 255.0f);   // exact fp32 math, matches reference
    int v = (int)(cv * 255.0f);
    int t = t_src[row];

    const float* fb = frames + (size_t)(b * 16 + t) * (3 * 256 * 256);
    unsigned short* xr = X + (size_t)row * KPAD;

#pragma unroll
    for (int it = 0; it < 4; ++it) {
        int kp = lane + it * 64;            // permuted index c*81 + i*9 + j
        unsigned short val = 0;
        if (kp < 243) {
            int c = kp / 81;
            int r = kp - c * 81;
            int i = r / 9;
            int j = r - i * 9;
            int y = v + i - 4; y = (y < 0) ? 0 : (y > 255 ? 255 : y);
            int x = u + j - 4; x = (x < 0) ? 0 : (x > 255 ? 255 : x);
            val = f2bf(fb[(size_t)c * 65536 + y * 256 + x]);
        }
        xr[kp] = val;
    }
}

// ---- MFMA GEMM body (shared by k_gemm1 / k_gemm2) -------------------------
// 128x256 tile / 8 waves (each 64x64 via 4x4 16x16x32). BK=64,
// SINGLE-buffered LDS: As 128x64 (16KB) + Bs 256x64 (32KB) = 48KB.
// XOR swizzle (as R3): logical 16B slot s of row r at physical slot s^(r&7);
// gll dest linear, source pre-swizzled (same involution on read).
// Grid FLAT 768 = 256 M-tiles x 3 N-tiles, XCD-chunk swizzled, y-fastest.
template <int K, bool GELU_, bool OUT_F32>
static __device__ __forceinline__
void gemm_body(const unsigned short* __restrict__ A,
               const unsigned short* __restrict__ BT,
               const float* __restrict__ bias,
               void* __restrict__ Cv) {
    __shared__ unsigned short As[128 * 64];   // 16 KB
    __shared__ unsigned short Bs[256 * 64];   // 32 KB

    const int tid  = threadIdx.x;
    const int wave = tid >> 6;      // 0..7
    const int lane = tid & 63;
    const int wr = wave >> 2;       // 0..1 : M half (64 rows of A)
    const int wc = wave & 3;        // 0..3 : N quarter (64 rows of BT)
    const int lm = lane & 15;
    const int lq = lane >> 4;

    // XCD-chunked bijective swizzle (nwg=768, 96/XCD), y-fastest so the 3
    // blocks sharing one A-panel are consecutive logical tiles -> same XCD L2.
    const int bid = blockIdx.x;
    const int swz = (bid & 7) * 96 + (bid >> 3);
    const int by  = swz % 3;
    const int bx  = swz / 3;
    const int m0 = bx * 128;
    const int n0 = by * 256;

    floatx4 acc[4][4];
#pragma unroll
    for (int i = 0; i < 4; ++i)
#pragma unroll
        for (int j = 0; j < 4; ++j)
            acc[i][j] = (floatx4){0.f, 0.f, 0.f, 0.f};

    const unsigned short* Ag = A  + (size_t)m0 * K;
    const unsigned short* Bg = BT + (size_t)n0 * K;

    // staging: chunk c = 8 rows x 64 cols = 1KB. A: 16 chunks, B: 32 chunks.
    // wave handles A-chunks {w, w+8}, B-chunks {w, w+8, w+16, w+24}.
    // lane l -> row c*8 + (l>>3), phys 16B slot l&7; source pre-swizzled
    // (logical slot = (l&7)^(l>>3) since (row&7) == l>>3).
    const int rl    = lane >> 3;
    const int pl    = lane & 7;
    const int lslot = pl ^ rl;
    const size_t so = (size_t)(lslot << 3);
    const size_t oA0 = (size_t)((wave)      * 8 + rl) * K + so;
    const size_t oA1 = (size_t)((wave + 8)  * 8 + rl) * K + so;
    const size_t oB0 = (size_t)((wave)      * 8 + rl) * K + so;
    const size_t oB1 = (size_t)((wave + 8)  * 8 + rl) * K + so;
    const size_t oB2 = (size_t)((wave + 16) * 8 + rl) * K + so;
    const size_t oB3 = (size_t)((wave + 24) * 8 + rl) * K + so;

    // frag read offsets (in shorts): row r, k-chunk s -> r*64 + ((s^(r&7))<<3)
    int aoff[2][4], boff[2][4];
#pragma unroll
    for (int mi = 0; mi < 4; ++mi) {
        int ra = wr * 64 + mi * 16 + lm;
        int rb = wc * 64 + mi * 16 + lm;
#pragma unroll
        for (int ks = 0; ks < 2; ++ks) {
            aoff[ks][mi] = ra * 64 + ((((ks << 2) + lq) ^ (ra & 7)) << 3);
            boff[ks][mi] = rb * 64 + ((((ks << 2) + lq) ^ (rb & 7)) << 3);
        }
    }

#define STAGE(K0) do {                                                         \
    __builtin_amdgcn_global_load_lds((g_void*)(Ag + oA0 + (K0)),               \
        (l_void*)(&As[(wave)      * 512]), 16, 0, 0);                          \
    __builtin_amdgcn_global_load_lds((g_void*)(Ag + oA1 + (K0)),               \
        (l_void*)(&As[(wave + 8)  * 512]), 16, 0, 0);                          \
    __builtin_amdgcn_global_load_lds((g_void*)(Bg + oB0 + (K0)),               \
        (l_void*)(&Bs[(wave)      * 512]), 16, 0, 0);                          \
    __builtin_amdgcn_global_load_lds((g_void*)(Bg + oB1 + (K0)),               \
        (l_void*)(&Bs[(wave + 8)  * 512]), 16, 0, 0);                          \
    __builtin_amdgcn_global_load_lds((g_void*)(Bg + oB2 + (K0)),               \
        (l_void*)(&Bs[(wave + 16) * 512]), 16, 0, 0);                          \
    __builtin_amdgcn_global_load_lds((g_void*)(Bg + oB3 + (K0)),               \
        (l_void*)(&Bs[(wave + 24) * 512]), 16, 0, 0);                          \
} while (0)

    // prologue: stage tile 0; syncthreads drains vmcnt -> tile 0 in LDS
    STAGE(0);
    __syncthreads();

#pragma unroll 1
    for (int k0 = 0; k0 < K; k0 += 64) {
        short8 fa0[4], fb0[4], fa1[4], fb1[4];
        // ks=0 frags
#pragma unroll
        for (int mi = 0; mi < 4; ++mi) fa0[mi] = *(const short8*)(&As[aoff[0][mi]]);
#pragma unroll
        for (int ni = 0; ni < 4; ++ni) fb0[ni] = *(const short8*)(&Bs[boff[0][ni]]);
        // MFMA ks=0 (32)
#pragma unroll
        for (int mi = 0; mi < 4; ++mi)
#pragma unroll
            for (int ni = 0; ni < 4; ++ni)
                acc[mi][ni] = __builtin_amdgcn_mfma_f32_16x16x32_bf16(
                    fa0[mi], fb0[ni], acc[mi][ni], 0, 0, 0);
        // ks=1 frags
#pragma unroll
        for (int mi = 0; mi < 4; ++mi) fa1[mi] = *(const short8*)(&As[aoff[1][mi]]);
#pragma unroll
        for (int ni = 0; ni < 4; ++ni) fb1[ni] = *(const short8*)(&Bs[boff[1][ni]]);

        __syncthreads();   // all waves done reading LDS (lgkm drained) -> free
        if (k0 + 64 < K)
            STAGE(k0 + 64);   // next tile flies under MFMA ks=1

        // MFMA ks=1 (32)
#pragma unroll
        for (int mi = 0; mi < 4; ++mi)
#pragma unroll
            for (int ni = 0; ni < 4; ++ni)
                acc[mi][ni] = __builtin_amdgcn_mfma_f32_16x16x32_bf16(
                    fa1[mi], fb1[ni], acc[mi][ni], 0, 0, 0);

        if (k0 + 64 < K)
            __syncthreads();   // drains vmcnt(0): next tile landed
    }
#undef STAGE

    // epilogue: D[row][col], row = lq*4 + r, col = lm within each 16x16 tile
#pragma unroll
    for (int ni = 0; ni < 4; ++ni) {
        int col = n0 + wc * 64 + ni * 16 + lm;
        float bs = bias[col];
#pragma unroll
        for (int mi = 0; mi < 4; ++mi) {
            int rowb = m0 + wr * 64 + mi * 16 + lq * 4;
#pragma unroll
            for (int r = 0; r < 4; ++r) {
                float x = acc[mi][ni][r] + bs;
                if (GELU_)
                    x = gelu_f(x);
                size_t idx = (size_t)(rowb + r) * EMB + col;
                if (OUT_F32)
                    ((float*)Cv)[idx] = x;
                else
                    ((unsigned short*)Cv)[idx] = f2bf(x);
            }
        }
    }
}

// distinct names so rocprof shows each GEMM separately
__global__ __launch_bounds__(512, 4)
void k_gemm1(const unsigned short* __restrict__ A, const unsigned short* __restrict__ BT,
             const float* __restrict__ bias, unsigned short* __restrict__ C) {
    gemm_body<KPAD, true, false>(A, BT, bias, (void*)C);
}

__global__ __launch_bounds__(512, 4)
void k_gemm2(const unsigned short* __restrict__ A, const unsigned short* __restrict__ BT,
             const float* __restrict__ bias, float* __restrict__ C) {
    gemm_body<EMB, false, true>(A, BT, bias, (void*)C);
}

// ---------------------------------------------------------------------------
extern "C" void kernel_launch(void* const* d_in, const int* in_sizes, int n_in,
                              void* d_out, int out_size, void* d_ws, size_t ws_size,
                              hipStream_t stream) {
    const float* frames = (const float*)d_in[0];
    const float* coords = (const float*)d_in[1];
    const int*   t_src  = (const int*)d_in[2];
    const float* W1     = (const float*)d_in[3];
    const float* b1     = (const float*)d_in[4];
    const float* W2     = (const float*)d_in[5];
    const float* b2     = (const float*)d_in[6];
    float* out = (float*)d_out;

    char* ws = (char*)d_ws;
    // workspace layout:
    //   X    : 32768*256*2 = 16,777,216 B  (bf16, permuted k')
    //   Hbuf : 32768*768*2 = 50,331,648 B  (bf16)
    //   W1T  : 768*256*2   =    393,216 B  (bf16, permuted k')
    //   W2T  : 768*768*2   =  1,179,648 B  (bf16)
    unsigned short* X    = (unsigned short*)(ws);
    unsigned short* Hbuf = (unsigned short*)(ws + 16777216);
    unsigned short* W1T  = (unsigned short*)(ws + 16777216 + 50331648);
    unsigned short* W2T  = (unsigned short*)(ws + 16777216 + 50331648 + 393216);

    // prep transposes (tiny)
    k_transpose_w1<<<768, 256, 0, stream>>>(W1, W1T);
    k_transpose_w2<<<dim3(24, 24), 256, 0, stream>>>(W2, W2T);

    // gather patches (one wave per row, channel-major element order)
    k_gather<<<M_ROWS / 4, 256, 0, stream>>>(frames, coords, t_src, X);

    // GEMM1: H = gelu(X @ W1 + b1)   (K = 256 padded), bf16 out
    k_gemm1<<<768, 512, 0, stream>>>(X, W1T, b1, Hbuf);

    // GEMM2: out = H @ W2 + b2       (K = 768), fp32 out
    k_gemm2<<<768, 512, 0, stream>>>(Hbuf, W2T, b2, out);
}